// Round 1
// 295.040 us; speedup vs baseline: 1.0617x; 1.0617x over previous
//
#include <hip/hip_runtime.h>

typedef __attribute__((ext_vector_type(8))) short short8;
typedef __attribute__((ext_vector_type(4))) float f32x4;
typedef unsigned int u32;

#define IN_F 256
#define OUT_F 128
#define NPB 256          // nodes per bucket (bucket = node >> 8)
#define MAXCAP 5120      // slots per bucket (mean 4092, +16 sigma)

__device__ __forceinline__ float bf2f(u32 u16) {
    union { u32 i; float f; } v; v.i = u16 << 16; return v.f;
}
__device__ __forceinline__ unsigned short f2bf(float f) {
    union { float f; u32 i; } v; v.f = f;
    u32 u = v.i;
    return (unsigned short)((u + 0x7fffu + ((u >> 16) & 1u)) >> 16);
}

// ---------------- pass 1: bucket-bin edges, packed (src<<8)|c_local ----------------
__global__ __launch_bounds__(256) void k_bin(const int* __restrict__ row, const int* __restrict__ col,
                                             int* __restrict__ bcur, int* __restrict__ ebuf,
                                             int E, int NBr, int chunk) {
    __shared__ int hist[512];
    __shared__ int cbase[512];
    int t = threadIdx.x;
    int e0 = blockIdx.x * chunk;
    int e1 = e0 + chunk; if (e1 > E) e1 = E;

    for (int i = t; i < NBr; i += 256) hist[i] = 0;
    __syncthreads();
    for (int i = e0 + t; i < e1; i += 256)
        atomicAdd(&hist[col[i] >> 8], 1);
    __syncthreads();
    for (int i = t; i < NBr; i += 256) {
        int h = hist[i];
        cbase[i] = h ? atomicAdd(&bcur[i], h) : 0;
    }
    __syncthreads();
    for (int i = t; i < NBr; i += 256) hist[i] = 0;
    __syncthreads();
    for (int i = e0 + t; i < e1; i += 256) {
        int c = col[i];
        int r = row[i];
        int b = c >> 8;
        int p = atomicAdd(&hist[b], 1) + cbase[b];
        ebuf[(size_t)b * MAXCAP + p] = (r << 8) | (c & 255);
    }
}

// ---------------- pass 2: per-bucket fine sort + deg/offs/dis, LDS atomics only ----------------
__global__ __launch_bounds__(256) void k_fine(const int* __restrict__ bcur, const int* __restrict__ ebuf,
                                              int* __restrict__ offs, int* __restrict__ deg,
                                              float* __restrict__ dis, int* __restrict__ srci, int N) {
    __shared__ int dl[256];
    __shared__ int sc[256];
    int b = blockIdx.x;
    int t = threadIdx.x;
    int count = bcur[b];
    const int* eb = ebuf + (size_t)b * MAXCAP;

    dl[t] = 0;
    __syncthreads();
    for (int i = t; i < count; i += 256)
        atomicAdd(&dl[eb[i] & 255], 1);
    __syncthreads();
    int myDeg = dl[t];
    // exclusive scan (Hillis-Steele)
    sc[t] = myDeg; __syncthreads();
    for (int off = 1; off < 256; off <<= 1) {
        int a = (t >= off) ? sc[t - off] : 0;
        __syncthreads();
        sc[t] += a;
        __syncthreads();
    }
    int excl = sc[t] - myDeg;
    int node = (b << 8) + t;
    int bbase = b * MAXCAP;
    if (node < N) {
        offs[node] = bbase + excl;
        deg[node] = myDeg;
        dis[node] = rsqrtf((float)myDeg + 1.0f);
    }
    dl[t] = excl;   // reuse as cursor
    __syncthreads();
    for (int i = t; i < count; i += 256) {
        int p = eb[i];
        int pos = atomicAdd(&dl[p & 255], 1);
        srci[bbase + pos] = p >> 8;    // stores within ~20 KB region -> L2-local
    }
}

// ---------------- transpose+convert W f32 -> fragment-linear bf16 ; zero hb row N ----
// Layout: for out-col n (ct=n>>4, mm=n&15), k (i=k>>5, q=(k>>3)&3, e=k&7):
//   Wt[ ((ct*8+i)*64 + q*16 + mm)*8 + e ] = bf16(W[k][n])
// so a wave's B-fragment for (ct, i) is 64 lanes x 16B CONTIGUOUS.
__global__ __launch_bounds__(256) void k_transposeW(const float* __restrict__ W,
                                                    unsigned short* __restrict__ Wt,
                                                    unsigned short* __restrict__ hb, int N) {
    int idx = blockIdx.x * 256 + threadIdx.x;
    if (idx < IN_F * OUT_F) {
        int k = idx >> 7;
        int n = idx & 127;
        int ct = n >> 4, mm = n & 15;
        int i = k >> 5, q = (k >> 3) & 3, e = k & 7;
        int d = (ct * 8 + i) * 64 + q * 16 + mm;
        Wt[(size_t)d * 8 + e] = f2bf(W[idx]);
    }
    if (idx < OUT_F) hb[(size_t)N * OUT_F + idx] = 0;
}

// ---------------- GEMM: hb[r][:] = bf16( (bf16(x[r]) @ W + b) * dis[r] ) ----------------
// 64 rows/block, 16 rows/wave. All 16 x-loads issued up front (full MLP);
// B staged once per block into LDS via global_load_lds (coalesced, fragment-linear).
__global__ __launch_bounds__(256) void k_gemm(const float* __restrict__ x,
                                              const unsigned short* __restrict__ Wt,
                                              const float* __restrict__ bias,
                                              const float* __restrict__ dis,
                                              unsigned short* __restrict__ hb, int nrows) {
    __shared__ short8 WB[4096];          // 64 KB fragment-linear B
    int wave = threadIdx.x >> 6;
    int lane = threadIdx.x & 63;
    int m = lane & 15;
    int quad = lane >> 4;

    int row0 = blockIdx.x * 64 + wave * 16;
    int nm1 = nrows - 1;
    int r = row0 + m; if (r > nm1) r = nm1;
    const float4* px = (const float4*)(x + (size_t)r * IN_F);

    // 1) issue ALL x-loads up front: 16 independent dwordx4 = 256B/lane in flight
    float4 xa[16];
#pragma unroll
    for (int i = 0; i < 8; i++) {
        xa[2 * i]     = px[8 * i + 2 * quad];
        xa[2 * i + 1] = px[8 * i + 2 * quad + 1];
    }

    // 2) stage B into LDS: each wave stages its contiguous 16KB quarter,
    //    1KB per global_load_lds_dwordx4 (64 lanes x 16B, linear both sides)
    {
        const char* gb = (const char*)Wt;
        char* lb = (char*)WB;
#pragma unroll
        for (int s = 0; s < 16; s++) {
            int d = (wave * 16 + s) * 64;
            __builtin_amdgcn_global_load_lds(
                (const __attribute__((address_space(1))) u32*)(gb + (size_t)(d + lane) * 16),
                (__attribute__((address_space(3))) u32*)(lb + (size_t)d * 16),
                16, 0, 0);
        }
    }

    float bv[8];
#pragma unroll
    for (int ct = 0; ct < 8; ct++) bv[ct] = bias[ct * 16 + m];

    __syncthreads();   // single latency payment: drains x-loads + LDS staging

    f32x4 acc[8];
#pragma unroll
    for (int ct = 0; ct < 8; ct++) acc[ct] = (f32x4){0.f, 0.f, 0.f, 0.f};

#pragma unroll
    for (int i = 0; i < 8; i++) {
        float4 a0 = xa[2 * i], a1 = xa[2 * i + 1];
        short8 af;
        af[0] = (short)f2bf(a0.x); af[1] = (short)f2bf(a0.y);
        af[2] = (short)f2bf(a0.z); af[3] = (short)f2bf(a0.w);
        af[4] = (short)f2bf(a1.x); af[5] = (short)f2bf(a1.y);
        af[6] = (short)f2bf(a1.z); af[7] = (short)f2bf(a1.w);
#pragma unroll
        for (int ct = 0; ct < 8; ct++) {
            short8 w = WB[ct * 512 + i * 64 + lane];   // ds_read_b128, contiguous per wave
            acc[ct] = __builtin_amdgcn_mfma_f32_16x16x32_bf16(af, w, acc[ct], 0, 0, 0);
        }
    }

    int orow0 = row0 + quad * 4;
#pragma unroll
    for (int rr = 0; rr < 4; rr++) {
        int orow = orow0 + rr;
        if (orow < nrows) {
            float dr = dis[orow];
#pragma unroll
            for (int ct = 0; ct < 8; ct++)
                hb[(size_t)orow * OUT_F + ct * 16 + m] = f2bf((acc[ct][rr] + bv[ct]) * dr);
        }
    }
}

// ---------------- aggregation: wave/node, coop src load + unroll-8 gathers, add-only ----------------
__global__ __launch_bounds__(256) void k_agg(const unsigned short* __restrict__ hb,
                                             const float* __restrict__ dis,
                                             const int* __restrict__ offs, const int* __restrict__ deg,
                                             const int* __restrict__ srci,
                                             float* __restrict__ out, int n) {
    int node = blockIdx.x * 4 + (threadIdx.x >> 6);
    if (node >= n) return;
    int lane = threadIdx.x & 63;

    unsigned int v = *(const unsigned int*)(hb + (size_t)node * OUT_F + lane * 2);
    float ax = bf2f(v & 0xffffu);
    float ay = bf2f(v >> 16);

    int start = offs[node];
    int cnt = deg[node];

    for (int base = 0; base < cnt; base += 64) {
        int mm = cnt - base; if (mm > 64) mm = 64;
        int e = (lane < mm) ? srci[start + base + lane] : n;
        int mround = (mm + 7) & ~7;
        for (int j = 0; j < mround; j += 8) {
            int rr[8];
#pragma unroll
            for (int k = 0; k < 8; k++) rr[k] = __shfl(e, j + k);
            unsigned int w[8];
#pragma unroll
            for (int k = 0; k < 8; k++)
                w[k] = *(const unsigned int*)(hb + (size_t)rr[k] * OUT_F + lane * 2);
#pragma unroll
            for (int k = 0; k < 8; k++) {
                ax += bf2f(w[k] & 0xffffu);
                ay += bf2f(w[k] >> 16);
            }
        }
    }

    float di = dis[node];
    float2 o;
    o.x = fmaxf(ax * di, 0.f);
    o.y = fmaxf(ay * di, 0.f);
    *(float2*)(out + (size_t)node * OUT_F + lane * 2) = o;
}

static inline size_t alignup(size_t v, size_t a) { return (v + a - 1) & ~(a - 1); }

extern "C" void kernel_launch(void* const* d_in, const int* in_sizes, int n_in,
                              void* d_out, int out_size, void* d_ws, size_t ws_size,
                              hipStream_t stream) {
    const float* x  = (const float*)d_in[0];
    const int* ei   = (const int*)d_in[1];
    const float* W  = (const float*)d_in[2];
    const float* b  = (const float*)d_in[3];
    float* out      = (float*)d_out;

    const int N = in_sizes[0] / IN_F;      // 100000
    const int E = in_sizes[1] / 2;         // 1600000
    const int* rowp = ei;
    const int* colp = ei + E;

    const int NBr = (N + NPB - 1) / NPB;   // 391 buckets (<= 512)

    // workspace carve (~44 MB total)
    char* ws = (char*)d_ws;
    size_t off = 0;
    int*   bcur   = (int*)(ws + off);   off = alignup(off + (size_t)NBr * 4, 256);
    int*   deg    = (int*)(ws + off);   off = alignup(off + (size_t)N * 4, 256);
    float* dis    = (float*)(ws + off); off = alignup(off + (size_t)N * 4, 256);
    int*   offs   = (int*)(ws + off);   off = alignup(off + (size_t)N * 4, 256);
    unsigned short* Wt = (unsigned short*)(ws + off); off = alignup(off + (size_t)IN_F * OUT_F * 2, 256);
    int*   ebuf   = (int*)(ws + off);   off = alignup(off + (size_t)NBr * MAXCAP * 4, 256);
    int*   srci   = (int*)(ws + off);   off = alignup(off + (size_t)NBr * MAXCAP * 4, 256);
    unsigned short* hb = (unsigned short*)(ws + off); off = alignup(off + (size_t)(N + 1) * OUT_F * 2, 256);

    (void)hipMemsetAsync(bcur, 0, (size_t)NBr * 4, stream);

    int chunk = (E + 511) / 512;           // 3125 edges/block
    k_bin<<<512, 256, 0, stream>>>(rowp, colp, bcur, ebuf, E, NBr, chunk);
    k_fine<<<NBr, 256, 0, stream>>>(bcur, ebuf, offs, deg, dis, srci, N);

    k_transposeW<<<(IN_F * OUT_F + 255) / 256, 256, 0, stream>>>(W, Wt, hb, N);
    k_gemm<<<(N + 63) / 64, 256, 0, stream>>>(x, Wt, b, dis, hb, N);

    k_agg<<<(N + 3) / 4, 256, 0, stream>>>(hb, dis, offs, deg, srci, out, N);
}